// Round 1
// baseline (680.510 us; speedup 1.0000x reference)
//
#include <hip/hip_runtime.h>
#include <math.h>

// Problem constants (fixed by setup_inputs)
#define B_ 4
#define C_ 64
#define N_ 16384
#define K_ 16
#define H_ 8
#define CP 67            // C + 3 (xyz concat)
#define CPAD 68          // padded to 17 float4
#define NP 16            // points per block
#define ESTRIDE 552      // e_lds row stride: 8*68 + 8 -> p-groups 8 banks apart
#define WSZ (C_ * CPAD)  // 4352 floats per weight matrix, TRANSPOSED layout [j][o]

// Padded / pre-scaled weights, TRANSPOSED to [j][o] so lane-k row reads coalesce
__device__ __align__(16) float wpad[3 * WSZ];

__global__ void setup_weights(const float* __restrict__ Wq,
                              const float* __restrict__ Wk,
                              const float* __restrict__ Wv) {
  int i = blockIdx.x * blockDim.x + threadIdx.x;
  if (i >= WSZ) return;
  int j = i >> 6, o = i & 63;          // wpad[j*64 + o] = W[o][j]
  float q = 0.f, kk = 0.f, v = 0.f;
  if (j < CP) {
    q = Wq[o * CP + j] * 0.35355339059327373f;  // fold 1/sqrt(D), D=8
    kk = Wk[o * CP + j];
    v = Wv[o * CP + j];
  }
  wpad[i] = q;
  wpad[WSZ + i] = kk;
  wpad[2 * WSZ + i] = v;
}

// XOR lane swizzle within 32-lane half (BitMode: and=0x1F, or=0, xor=mask)
#define SWZ(v, imm) __int_as_float(__builtin_amdgcn_ds_swizzle(__float_as_int(v), (imm)))
#define XOR4 0x101F

// DPP lane exchange on the VALU pipe (no DS, no lgkmcnt):
//   quad_perm 0xB1 = XOR1, 0x4E = XOR2, row_ror:8 = XOR8 within a 16-lane row,
//   row_ror:4 = rotate-by-4 (valid for all-reduce after quad stages).
#define DPP_XOR1 0xB1
#define DPP_XOR2 0x4E
#define DPP_ROR4 0x124
#define DPP_ROR8 0x128
template <int CTRL>
__device__ __forceinline__ float dppf(float x) {
  int i = __float_as_int(x);
  return __int_as_float(__builtin_amdgcn_update_dpp(i, i, CTRL, 0xF, 0xF, false));
}

__launch_bounds__(256, 4)
__global__ void pt_attn(const float* __restrict__ pcd,
                        const float* __restrict__ neighbors,
                        const float* __restrict__ xyz,
                        const int* __restrict__ idx_all,
                        float* __restrict__ out) {
  // x_lds: pcd_cat tile (16*68 floats); reused after phase 1 as the 64x17 output transpose
  __shared__ __align__(16) float x_lds[NP * CPAD];
  __shared__ __align__(16) float e_lds[NP * ESTRIDE]; // e[h][j] = Wk_h^T q_h

  const int tid = threadIdx.x;
  const int p = tid >> 4;   // point within tile
  const int k = tid & 15;   // neighbor index
  const int blk = blockIdx.x;
  const int b = blk >> 10;             // N/NP = 1024 tiles per batch
  const int n0 = (blk & 1023) << 4;
  const int n = n0 + p;

  // ---- neighbor features (B,C,N,K) -> registers; perfectly coalesced ----
  float nb[CPAD];
  {
    const float* gp = neighbors + (size_t)b * (C_ * N_ * K_) + n0 * K_ + tid;
#pragma unroll
    for (int c = 0; c < C_; ++c)
      nb[c] = gp[(size_t)c * (N_ * K_)];
  }
  {
    const int idx = idx_all[(b * N_ + n) * K_ + k];
    const float* gx = xyz + (size_t)b * (3 * N_) + idx;
    nb[64] = gx[0];
    nb[65] = gx[N_];
    nb[66] = gx[2 * N_];
    nb[67] = 0.f;  // pad (weights pad col is 0 too)
  }

  // ---- stage x67 = concat(pcd, xyz) for the 16 points ----
  {
    const int pp = tid & 15;
    const int c0 = tid >> 4;  // 0..15
#pragma unroll
    for (int it = 0; it < 4; ++it) {
      int c = c0 + it * 16;
      x_lds[pp * CPAD + c] = pcd[((size_t)b * C_ + c) * N_ + n0 + pp];
    }
    if (tid < 48)
      x_lds[pp * CPAD + 64 + c0] = xyz[((size_t)b * 3 + c0) * N_ + n0 + pp];
    if (tid < 16)
      x_lds[pp * CPAD + 67] = 0.f;
  }
  __syncthreads();

  // ---- phase 1: lane k computes q[qb..qb+3], qb = 8*(k&7) + 4*(k>>3)
  //      (so phase 2's head-h gather is a single in-wave XOR8 exchange).
  //      wpad is [j][o]: lanes read 16 contiguous float4 -> fully coalesced. ----
  const int h = k & 7;
  float a0 = 0.f, a1 = 0.f, a2 = 0.f, a3 = 0.f;
  {
    const float4* xr = (const float4*)(x_lds + p * CPAD);
    const float* wq = wpad + 8 * h + 4 * (k >> 3);
#pragma unroll
    for (int j4 = 0; j4 < 17; ++j4) {
      float4 xv = xr[j4];
      float4 w0 = *(const float4*)(wq + (4 * j4 + 0) * 64);
      float4 w1 = *(const float4*)(wq + (4 * j4 + 1) * 64);
      float4 w2 = *(const float4*)(wq + (4 * j4 + 2) * 64);
      float4 w3 = *(const float4*)(wq + (4 * j4 + 3) * 64);
      a0 += w0.x * xv.x + w1.x * xv.y + w2.x * xv.z + w3.x * xv.w;
      a1 += w0.y * xv.x + w1.y * xv.y + w2.y * xv.z + w3.y * xv.w;
      a2 += w0.z * xv.x + w1.z * xv.y + w2.z * xv.z + w3.z * xv.w;
      a3 += w0.w * xv.x + w1.w * xv.y + w2.w * xv.z + w3.w * xv.w;
    }
  }

  // ---- phase 2: gather q[8h..8h+7] via DPP ror:8 (lanes k <-> k^8 hold the
  //      two halves), then e[h][j-half] -> e_lds. No barrier needed: producer
  //      and consumer lanes are the same 16-lane group (same wave). ----
  {
    float b0 = dppf<DPP_ROR8>(a0);
    float b1 = dppf<DPP_ROR8>(a1);
    float b2 = dppf<DPP_ROR8>(a2);
    float b3 = dppf<DPP_ROR8>(a3);
    const bool hi = (k & 8) != 0;
    float qa0 = hi ? b0 : a0, qa1 = hi ? b1 : a1;
    float qa2 = hi ? b2 : a2, qa3 = hi ? b3 : a3;
    float qa4 = hi ? a0 : b0, qa5 = hi ? a1 : b1;
    float qa6 = hi ? a2 : b2, qa7 = hi ? a3 : b3;

    const float* wk = wpad + WSZ + 8 * h;   // [j][o] rows 8h..8h+7
    float4* er = (float4*)(e_lds + p * ESTRIDE + h * CPAD);
    const int jb = (k >> 3) * 8;
#pragma unroll
    for (int u = 0; u < 9; ++u) {           // j4==8 duplicated by both halves (identical)
      int j4 = jb + u;
      float r[4];
#pragma unroll
      for (int jj = 0; jj < 4; ++jj) {
        const float4 wlo = *(const float4*)(wk + (4 * j4 + jj) * 64);
        const float4 whi = *(const float4*)(wk + (4 * j4 + jj) * 64 + 4);
        r[jj] = qa0 * wlo.x + qa1 * wlo.y + qa2 * wlo.z + qa3 * wlo.w +
                qa4 * whi.x + qa5 * whi.y + qa6 * whi.z + qa7 * whi.w;
      }
      er[j4] = make_float4(r[0], r[1], r[2], r[3]);
    }
  }
  // wave-local: make this wave's e_lds writes visible to its own lanes' reads
  asm volatile("s_waitcnt lgkmcnt(0)" ::: "memory");
  __builtin_amdgcn_sched_barrier(0);

  // ---- phase 3: energies en[h] = e[h]·nb_k (scale folded), softmax over k.
  //      e reads are 16-lane broadcasts; softmax reduce is pure DPP. ----
  float en[8];
#pragma unroll
  for (int hh = 0; hh < 8; ++hh) en[hh] = 0.f;
  {
    const float4* ep = (const float4*)(e_lds + p * ESTRIDE);
#pragma unroll
    for (int j4 = 0; j4 < 17; ++j4) {
#pragma unroll
      for (int hh = 0; hh < 8; ++hh) {
        float4 e4 = ep[hh * 17 + j4];
        en[hh] += e4.x * nb[4 * j4 + 0] + e4.y * nb[4 * j4 + 1] +
                  e4.z * nb[4 * j4 + 2] + e4.w * nb[4 * j4 + 3];
      }
    }
  }
  float at[8];
#pragma unroll
  for (int hh = 0; hh < 8; ++hh) {
    float m = en[hh];
    m = fmaxf(m, dppf<DPP_XOR1>(m));
    m = fmaxf(m, dppf<DPP_XOR2>(m));
    m = fmaxf(m, dppf<DPP_ROR4>(m));  // after quad all-reduce, ror4+ror8 completes 16 lanes
    m = fmaxf(m, dppf<DPP_ROR8>(m));
    float e = __expf(en[hh] - m);
    float s = e;
    s += dppf<DPP_XOR1>(s);
    s += dppf<DPP_XOR2>(s);
    s += dppf<DPP_ROR4>(s);
    s += dppf<DPP_ROR8>(s);
    at[hh] = e * __builtin_amdgcn_rcpf(s);
  }

  // ---- permuted attn for the DPP reduce-scatter. Stage order is
  //      XOR8 (DPP ror:8), XOR2 (quad), XOR1 (quad), XOR4 (lone ds_swizzle),
  //      pairing value bits (2,1,0) with lane bits (3,1,0); lane bit 2 is the
  //      duplicate dimension. Hence g' = k.b3<<2 | k.b1<<1 | k.b0, and lane k
  //      ends holding agg for head g'; it applies Wv rows ob = 8*g' + (k&4). ----
  const int g = (((k >> 3) & 1) << 2) | (((k >> 1) & 1) << 1) | (k & 1);
  float ap[8];
  {
    float t0[8], t1[8];
#pragma unroll
    for (int i = 0; i < 8; ++i) t0[i] = (k & 8) ? at[i ^ 4] : at[i];
#pragma unroll
    for (int i = 0; i < 8; ++i) t1[i] = (k & 2) ? t0[i ^ 2] : t0[i];
#pragma unroll
    for (int i = 0; i < 8; ++i) ap[i] = (k & 1) ? t1[i ^ 1] : t1[i];
  }

  // ---- phase 4: agg_h[j] = sum_k attn[h,k]*nb_k[j]; 7 DPP adds + 1 swizzle
  //      per element (was 8 ds_swizzles). Wv via transposed layout: coalesced. ----
  const int ob = 8 * g + (k & 4);
  float xo0 = 0.f, xo1 = 0.f, xo2 = 0.f, xo3 = 0.f;
  {
    const float* wv = wpad + 2 * WSZ + ob;
#pragma unroll
    for (int j4 = 0; j4 < 17; ++j4) {
      float agg0, agg1, agg2, agg3;
#pragma unroll
      for (int u = 0; u < 4; ++u) {
        float nbj = nb[4 * j4 + u];
        float s0 = ap[0] * nbj, s1 = ap[1] * nbj, s2 = ap[2] * nbj, s3 = ap[3] * nbj;
        float s4 = ap[4] * nbj, s5 = ap[5] * nbj, s6 = ap[6] * nbj, s7 = ap[7] * nbj;
        s0 += dppf<DPP_ROR8>(s4);   // XOR8: value bit2 <-> lane bit3
        s1 += dppf<DPP_ROR8>(s5);
        s2 += dppf<DPP_ROR8>(s6);
        s3 += dppf<DPP_ROR8>(s7);
        s0 += dppf<DPP_XOR2>(s2);   // XOR2: value bit1 <-> lane bit1
        s1 += dppf<DPP_XOR2>(s3);
        s0 += dppf<DPP_XOR1>(s1);   // XOR1: value bit0 <-> lane bit0
        s0 += SWZ(s0, XOR4);        // lane bit2: duplicate-pair reduce (only DS op)
        if (u == 0) agg0 = s0;
        else if (u == 1) agg1 = s0;
        else if (u == 2) agg2 = s0;
        else agg3 = s0;
      }
      float4 w0 = *(const float4*)(wv + (4 * j4 + 0) * 64);
      float4 w1 = *(const float4*)(wv + (4 * j4 + 1) * 64);
      float4 w2 = *(const float4*)(wv + (4 * j4 + 2) * 64);
      float4 w3 = *(const float4*)(wv + (4 * j4 + 3) * 64);
      xo0 += w0.x * agg0 + w1.x * agg1 + w2.x * agg2 + w3.x * agg3;
      xo1 += w0.y * agg0 + w1.y * agg1 + w2.y * agg2 + w3.y * agg3;
      xo2 += w0.z * agg0 + w1.z * agg1 + w2.z * agg2 + w3.z * agg3;
      xo3 += w0.w * agg0 + w1.w * agg1 + w2.w * agg2 + w3.w * agg3;
    }
  }

  // ---- store: transpose through freed x_lds (64 rows x 17 pad = 1088 floats,
  //      exact reuse) so each thread emits ONE coalesced dwordx4 store. ----
  __syncthreads();  // all waves past phase-1 x_lds reads
  {
    float* ol = x_lds;
    ol[(ob + 0) * 17 + p] = xo0;
    ol[(ob + 1) * 17 + p] = xo1;
    ol[(ob + 2) * 17 + p] = xo2;
    ol[(ob + 3) * 17 + p] = xo3;
  }
  __syncthreads();
  {
    const int o = tid >> 2;           // 0..63
    const int pc = (tid & 3) << 2;    // 0,4,8,12
    const float* ol = x_lds + o * 17 + pc;
    float4 vo = make_float4(ol[0], ol[1], ol[2], ol[3]);
    *(float4*)(out + ((size_t)b * C_ + o) * N_ + n0 + pc) = vo;
  }
}

extern "C" void kernel_launch(void* const* d_in, const int* in_sizes, int n_in,
                              void* d_out, int out_size, void* d_ws, size_t ws_size,
                              hipStream_t stream) {
  const float* pcd = (const float*)d_in[0];
  const float* neighbors = (const float*)d_in[1];
  const float* xyz = (const float*)d_in[2];
  const float* Wq = (const float*)d_in[3];
  const float* Wk = (const float*)d_in[4];
  const float* Wv = (const float*)d_in[5];
  const int* idx = (const int*)d_in[6];
  float* out = (float*)d_out;

  setup_weights<<<(WSZ + 255) / 256, 256, 0, stream>>>(Wq, Wk, Wv);
  pt_attn<<<B_ * (N_ / NP), 256, 0, stream>>>(pcd, neighbors, xyz, idx, out);
}